// Round 4
// baseline (330.950 us; speedup 1.0000x reference)
//
#include <hip/hip_runtime.h>

// Problem dims (fixed by setup_inputs): x [B,N,C], adapter dim D, patch grid HxH
#define B_  64
#define N_  1024
#define H_  32
#define C_  768
#define D_  8

__device__ __forceinline__ float qgelu(float v) {
    // v * sigmoid(1.702 v) = v / (1 + exp(-1.702 v))
    return v / (1.0f + __expf(-1.702f * v));
}

// 10-shuffle butterfly reduce over d=8: halve d at xor1/2/4, broadcast 8/16/32.
// On return acc[0] holds, in lane l, the full sum for
// dl(l) = 4*(l&1) + 2*((l>>1)&1) + ((l>>2)&1)  (all 8-lane groups identical).
__device__ __forceinline__ void reduce8(float* acc, int lane) {
    {
        const bool hi = lane & 1;
#pragma unroll
        for (int j = 0; j < 4; ++j) {
            const float a = acc[j], b = acc[j + 4];
            acc[j] = hi ? b : a;
            acc[j + 4] = hi ? a : b;
        }
#pragma unroll
        for (int j = 0; j < 4; ++j)
            acc[j] += __shfl_xor(acc[j + 4], 1, 64);
    }
    {
        const bool hi = lane & 2;
#pragma unroll
        for (int j = 0; j < 2; ++j) {
            const float a = acc[j], b = acc[j + 2];
            acc[j] = hi ? b : a;
            acc[j + 2] = hi ? a : b;
        }
#pragma unroll
        for (int j = 0; j < 2; ++j)
            acc[j] += __shfl_xor(acc[j + 2], 2, 64);
    }
    {
        const bool hi = lane & 4;
        const float a = acc[0], b = acc[1];
        acc[0] = hi ? b : a;
        acc[1] = hi ? a : b;
        acc[0] += __shfl_xor(acc[1], 4, 64);
    }
    acc[0] += __shfl_xor(acc[0], 8, 64);
    acc[0] += __shfl_xor(acc[0], 16, 64);
    acc[0] += __shfl_xor(acc[0], 32, 64);
}

// ---------------- Kernel 1: x_down = quick_gelu(x @ Wd + bd) ----------------
// v4: occupancy/MLP-first. Weights in LDS (amortized 4 rows per b128 read);
// each wave owns 16 CONTIGUOUS rows, processed 4 rows/iteration with all
// 12 float4 loads issued before any use (12 KB in flight per wave).
// 4 blocks/CU (VGPR<=128) = 16 waves/CU.
__global__ __launch_bounds__(256, 4) void k_down(
    const float* __restrict__ x, const float* __restrict__ Wd,
    const float* __restrict__ bd, float* __restrict__ t1, int nrows)
{
    __shared__ float sW[D_ * C_];   // transposed: sW[d*C_ + c] = Wd[c*D_ + d]
    for (int i = threadIdx.x; i < D_ * C_; i += 256) {
        int d = i / C_, c = i - d * C_;
        sW[i] = Wd[c * D_ + d];
    }
    __syncthreads();

    const int wid  = threadIdx.x >> 6;
    const int lane = threadIdx.x & 63;
    const int dl   = 4 * (lane & 1) + 2 * ((lane >> 1) & 1) + ((lane >> 2) & 1);
    const float bias = bd[dl];

    const int wave = blockIdx.x * 4 + wid;      // 4096 waves cover 65536 rows
    const int row0 = wave * 16;                 // 16 contiguous rows per wave
    if (row0 >= nrows) return;

#pragma unroll 1
    for (int it = 0; it < 4; ++it) {
        const int r = row0 + it * 4;
        const float4* xp = (const float4*)(x + (size_t)r * C_); // 4 rows = 768 f4

        // issue all 12 loads (3 KB/row x 4 rows) before any use
        float4 v[4][3];
#pragma unroll
        for (int rr = 0; rr < 4; ++rr)
#pragma unroll
            for (int k = 0; k < 3; ++k)
                v[rr][k] = xp[rr * 192 + k * 64 + lane];

        float a0[D_], a1[D_], a2[D_], a3[D_];
#pragma unroll
        for (int d = 0; d < D_; ++d) { a0[d]=0.f; a1[d]=0.f; a2[d]=0.f; a3[d]=0.f; }

#pragma unroll
        for (int k = 0; k < 3; ++k) {
#pragma unroll
            for (int d = 0; d < D_; ++d) {
                const float4 w = *(const float4*)&sW[d * C_ + (k * 64 + lane) * 4];
                a0[d] += v[0][k].x*w.x + v[0][k].y*w.y + v[0][k].z*w.z + v[0][k].w*w.w;
                a1[d] += v[1][k].x*w.x + v[1][k].y*w.y + v[1][k].z*w.z + v[1][k].w*w.w;
                a2[d] += v[2][k].x*w.x + v[2][k].y*w.y + v[2][k].z*w.z + v[2][k].w*w.w;
                a3[d] += v[3][k].x*w.x + v[3][k].y*w.y + v[3][k].z*w.z + v[3][k].w*w.w;
            }
        }

        reduce8(a0, lane);
        reduce8(a1, lane);
        reduce8(a2, lane);
        reduce8(a3, lane);

        if (lane < 32) {
            const int rr = lane >> 3;
            float s = (rr == 0) ? a0[0] : (rr == 1) ? a1[0] : (rr == 2) ? a2[0] : a3[0];
            t1[(size_t)(r + rr) * D_ + dl] = qgelu(s + bias);
        }
    }
}

// ------------- Kernel 2: t2 = quick_gelu(conv3x3(t1) + bc) ------------------
// (unchanged from R3)
__global__ __launch_bounds__(256, 4) void k_conv(
    const float* __restrict__ t1, const float* __restrict__ Wc,
    const float* __restrict__ bc, float* __restrict__ t2)
{
    __shared__ float sIn[10 * H_ * D_];     // 10 rows x 32 cols x 8 ch = 10 KB
    __shared__ float sWc[9 * D_ * D_];      // 2304 B, layout [kh][kw][ci][co]
    __shared__ float sbc[D_];

    const int img   = blockIdx.x >> 2;
    const int strip = blockIdx.x & 3;
    const int h0    = strip * 8;
    const float* in = t1 + (size_t)img * N_ * D_;

#pragma unroll
    for (int j = 0; j < 10; ++j) {
        const int i  = threadIdx.x + j * 256;
        const int lr = i >> 8;
        const int rem = i & 255;
        const int g  = h0 - 1 + lr;
        sIn[i] = (g >= 0 && g < H_) ? in[(size_t)g * H_ * D_ + rem] : 0.0f;
    }
    for (int i = threadIdx.x; i < 9 * D_ * D_; i += 256) sWc[i] = Wc[i];
    if (threadIdx.x < D_) sbc[threadIdx.x] = bc[threadIdx.x];
    __syncthreads();

    const int lh = threadIdx.x >> 5;
    const int w  = threadIdx.x & 31;
    float acc[D_];
#pragma unroll
    for (int co = 0; co < D_; ++co) acc[co] = sbc[co];

#pragma unroll
    for (int kh = 0; kh < 3; ++kh) {
        const int lrow = lh + kh;
#pragma unroll
        for (int kw = 0; kw < 3; ++kw) {
            const int ww = w + kw - 1;
            if (ww < 0 || ww >= H_) continue;
            const float* ip = &sIn[(lrow * H_ + ww) * D_];
            const float* wp = &sWc[(kh * 3 + kw) * D_ * D_];
#pragma unroll
            for (int ci = 0; ci < D_; ++ci) {
                const float iv = ip[ci];
#pragma unroll
                for (int co = 0; co < D_; ++co)
                    acc[co] += iv * wp[ci * D_ + co];
            }
        }
    }
    float4 o0, o1;
    o0.x = qgelu(acc[0]); o0.y = qgelu(acc[1]);
    o0.z = qgelu(acc[2]); o0.w = qgelu(acc[3]);
    o1.x = qgelu(acc[4]); o1.y = qgelu(acc[5]);
    o1.z = qgelu(acc[6]); o1.w = qgelu(acc[7]);
    float* tp = t2 + ((size_t)img * N_ + (size_t)(h0 + lh) * H_ + w) * D_;
    *(float4*)tp       = o0;
    *(float4*)(tp + 4) = o1;
}

// ---------------- Kernel 3: out = t2 @ Wu + bu ------------------------------
// (unchanged from R3: register-weight, LDS-free, write-bound)
__global__ __launch_bounds__(256, 3) void k_up(
    const float* __restrict__ t2, const float* __restrict__ Wu,
    const float* __restrict__ bu, float* __restrict__ out, int nrows)
{
    const int wid  = threadIdx.x >> 6;
    const int lane = threadIdx.x & 63;

    float4 w[3][D_];
    float4 bias[3];
#pragma unroll
    for (int j = 0; j < 3; ++j) {
        bias[j] = *(const float4*)&bu[(lane + j * 64) * 4];
#pragma unroll
        for (int d = 0; d < D_; ++d)
            w[j][d] = *(const float4*)&Wu[d * C_ + (lane + j * 64) * 4];
    }

    const int stride = gridDim.x * 4;
    for (int row = blockIdx.x * 4 + wid; row < nrows; row += stride) {
        const float4* rp = (const float4*)(t2 + (size_t)row * D_);
        const float4 ra = rp[0];
        const float4 rb = rp[1];
        const float rv[D_] = { ra.x, ra.y, ra.z, ra.w, rb.x, rb.y, rb.z, rb.w };

#pragma unroll
        for (int j = 0; j < 3; ++j) {
            float4 o = bias[j];
#pragma unroll
            for (int d = 0; d < D_; ++d) {
                o.x += rv[d] * w[j][d].x;
                o.y += rv[d] * w[j][d].y;
                o.z += rv[d] * w[j][d].z;
                o.w += rv[d] * w[j][d].w;
            }
            *(float4*)&out[(size_t)row * C_ + (size_t)(lane + j * 64) * 4] = o;
        }
    }
}

extern "C" void kernel_launch(void* const* d_in, const int* in_sizes, int n_in,
                              void* d_out, int out_size, void* d_ws, size_t ws_size,
                              hipStream_t stream) {
    const float* x  = (const float*)d_in[0];
    const float* Wd = (const float*)d_in[1];
    const float* bd = (const float*)d_in[2];
    const float* Wc = (const float*)d_in[3];
    const float* bc = (const float*)d_in[4];
    const float* Wu = (const float*)d_in[5];
    const float* bu = (const float*)d_in[6];
    float* out = (float*)d_out;

    const int nrows = B_ * N_;                  // 65536
    float* t1 = (float*)d_ws;                   // [nrows][D_]  (2 MB)
    float* t2 = t1 + (size_t)nrows * D_;        // [nrows][D_]  (2 MB)

    // K1 v4: 1024 blocks = 4/CU resident, each wave streams 16 contiguous rows.
    // PROBE: launched twice (identical, deterministic) so k_down time can be
    // recovered from the total: k_down ~= (dur_us - 27.4) / 2.
    k_down<<<1024, 256, 0, stream>>>(x, Wd, bd, t1, nrows);
    k_down<<<1024, 256, 0, stream>>>(x, Wd, bd, t1, nrows);
    // K2: 4 blocks per image (unchanged)
    k_conv<<<B_ * 4, 256, 0, stream>>>(t1, Wc, bc, t2);
    // K3: register-weight, LDS-free (unchanged)
    k_up<<<768, 256, 0, stream>>>(t2, Wu, bu, out, nrows);
}

// Round 5
// 108.190 us; speedup vs baseline: 3.0590x; 3.0590x over previous
//
#include <hip/hip_runtime.h>

// Problem dims (fixed by setup_inputs): x [B,N,C], adapter dim D, patch grid HxH
#define B_  64
#define N_  1024
#define H_  32
#define C_  768
#define D_  8

__device__ __forceinline__ float qgelu(float v) {
    // v * sigmoid(1.702 v) = v / (1 + exp(-1.702 v))
    return v / (1.0f + __expf(-1.702f * v));
}

// async 16-byte global->LDS DMA (wave-uniform LDS base + lane*16 dest)
__device__ __forceinline__ void async_cp16(const float* gp, float* lp) {
    __builtin_amdgcn_global_load_lds(
        (const __attribute__((address_space(1))) void*)gp,
        (__attribute__((address_space(3))) void*)lp, 16, 0, 0);
}

// 10-shuffle butterfly reduce over d=8: halve d at xor1/2/4, broadcast 8/16/32.
// On return acc[0] holds, in lane l, the full sum for
// dl(l) = 4*(l&1) + 2*((l>>1)&1) + ((l>>2)&1)  (all 8-lane groups identical).
__device__ __forceinline__ void reduce8(float* acc, int lane) {
    {
        const bool hi = lane & 1;
#pragma unroll
        for (int j = 0; j < 4; ++j) {
            const float a = acc[j], b = acc[j + 4];
            acc[j] = hi ? b : a;
            acc[j + 4] = hi ? a : b;
        }
#pragma unroll
        for (int j = 0; j < 4; ++j)
            acc[j] += __shfl_xor(acc[j + 4], 1, 64);
    }
    {
        const bool hi = lane & 2;
#pragma unroll
        for (int j = 0; j < 2; ++j) {
            const float a = acc[j], b = acc[j + 2];
            acc[j] = hi ? b : a;
            acc[j + 2] = hi ? a : b;
        }
#pragma unroll
        for (int j = 0; j < 2; ++j)
            acc[j] += __shfl_xor(acc[j + 2], 2, 64);
    }
    {
        const bool hi = lane & 4;
        const float a = acc[0], b = acc[1];
        acc[0] = hi ? b : a;
        acc[1] = hi ? a : b;
        acc[0] += __shfl_xor(acc[1], 4, 64);
    }
    acc[0] += __shfl_xor(acc[0], 8, 64);
    acc[0] += __shfl_xor(acc[0], 16, 64);
    acc[0] += __shfl_xor(acc[0], 32, 64);
}

// ---------------- Kernel 1: x_down = quick_gelu(x @ Wd + bd) ----------------
// v5: DMA-staged streaming. Double-buffered LDS x-tiles (8 rows = 24 KB each)
// filled via global_load_lds (24 x 1KB in flight per block, no VGPR round
// trip). Per tile each wave computes 2 rows from LDS against register
// weights. Compute (~0.5us) hides under transfer (~2us) -> BW-bound.
__global__ __launch_bounds__(256, 2) void k_down(
    const float* __restrict__ x, const float* __restrict__ Wd,
    const float* __restrict__ bd, float* __restrict__ t1, int nrows)
{
    __shared__ float buf[2][D_ * C_];          // 2 x 6144 floats = 48 KB

    const int wid  = threadIdx.x >> 6;
    const int lane = threadIdx.x & 63;

    // ---- one-time: transpose Wd through buf[0] into 96 register VGPRs ----
    for (int i = threadIdx.x; i < D_ * C_; i += 256) {
        const int c = i >> 3, d = i & 7;
        buf[0][d * C_ + c] = Wd[i];            // Wd is [C][D] row-major
    }
    __syncthreads();
    float4 w[3][D_];
#pragma unroll
    for (int k = 0; k < 3; ++k)
#pragma unroll
        for (int d = 0; d < D_; ++d)
            w[k][d] = *(const float4*)&buf[0][d * C_ + (k * 64 + lane) * 4];
    const int dl = 4 * (lane & 1) + 2 * ((lane >> 1) & 1) + ((lane >> 2) & 1);
    const float bias = bd[dl];
    __syncthreads();

    // ---- pipeline over 16 tiles of 8 rows (block owns 128 contiguous rows)
    const int row0 = blockIdx.x * 128;

    // stage(t, b): rows row0+8t .. +8 -> buf[b]; 6 x 1KB DMA per wave
#define STAGE(T, BUF)                                                        \
    {                                                                        \
        const float* gp0 = x + (size_t)(row0 + (T) * 8) * C_ + wid * 1536;   \
        float* lp0 = &buf[BUF][wid * 1536];                                  \
        _Pragma("unroll")                                                    \
        for (int j = 0; j < 6; ++j)                                          \
            async_cp16(gp0 + j * 256 + lane * 4, lp0 + j * 256);             \
    }

    STAGE(0, 0)
#pragma unroll 1
    for (int t = 0; t < 16; ++t) {
        __syncthreads();                        // vmcnt drain: buf[t&1] ready
        if (t + 1 < 16) STAGE(t + 1, (t + 1) & 1)

        // compute 2 rows of tile t from LDS
        const float* rowa = &buf[t & 1][(2 * wid) * C_];
        const float* rowb = rowa + C_;
        float a0[D_], a1[D_];
#pragma unroll
        for (int d = 0; d < D_; ++d) { a0[d] = 0.f; a1[d] = 0.f; }
#pragma unroll
        for (int k = 0; k < 3; ++k) {
            const float4 va = *(const float4*)&rowa[(k * 64 + lane) * 4];
            const float4 vb = *(const float4*)&rowb[(k * 64 + lane) * 4];
#pragma unroll
            for (int d = 0; d < D_; ++d) {
                a0[d] += va.x * w[k][d].x + va.y * w[k][d].y
                       + va.z * w[k][d].z + va.w * w[k][d].w;
                a1[d] += vb.x * w[k][d].x + vb.y * w[k][d].y
                       + vb.z * w[k][d].z + vb.w * w[k][d].w;
            }
        }
        reduce8(a0, lane);
        reduce8(a1, lane);

        if (lane < 16) {
            const float s = (lane & 8) ? a1[0] : a0[0];
            const int   r = row0 + t * 8 + 2 * wid + ((lane >> 3) & 1);
            t1[(size_t)r * D_ + dl] = qgelu(s + bias);
        }
        __syncthreads();                        // all waves done with buf[t&1]
    }
#undef STAGE
}

// ------------- Kernel 2: t2 = quick_gelu(conv3x3(t1) + bc) ------------------
// (unchanged)
__global__ __launch_bounds__(256, 4) void k_conv(
    const float* __restrict__ t1, const float* __restrict__ Wc,
    const float* __restrict__ bc, float* __restrict__ t2)
{
    __shared__ float sIn[10 * H_ * D_];     // 10 rows x 32 cols x 8 ch = 10 KB
    __shared__ float sWc[9 * D_ * D_];
    __shared__ float sbc[D_];

    const int img   = blockIdx.x >> 2;
    const int strip = blockIdx.x & 3;
    const int h0    = strip * 8;
    const float* in = t1 + (size_t)img * N_ * D_;

#pragma unroll
    for (int j = 0; j < 10; ++j) {
        const int i  = threadIdx.x + j * 256;
        const int lr = i >> 8;
        const int rem = i & 255;
        const int g  = h0 - 1 + lr;
        sIn[i] = (g >= 0 && g < H_) ? in[(size_t)g * H_ * D_ + rem] : 0.0f;
    }
    for (int i = threadIdx.x; i < 9 * D_ * D_; i += 256) sWc[i] = Wc[i];
    if (threadIdx.x < D_) sbc[threadIdx.x] = bc[threadIdx.x];
    __syncthreads();

    const int lh = threadIdx.x >> 5;
    const int w  = threadIdx.x & 31;
    float acc[D_];
#pragma unroll
    for (int co = 0; co < D_; ++co) acc[co] = sbc[co];

#pragma unroll
    for (int kh = 0; kh < 3; ++kh) {
        const int lrow = lh + kh;
#pragma unroll
        for (int kw = 0; kw < 3; ++kw) {
            const int ww = w + kw - 1;
            if (ww < 0 || ww >= H_) continue;
            const float* ip = &sIn[(lrow * H_ + ww) * D_];
            const float* wp = &sWc[(kh * 3 + kw) * D_ * D_];
#pragma unroll
            for (int ci = 0; ci < D_; ++ci) {
                const float iv = ip[ci];
#pragma unroll
                for (int co = 0; co < D_; ++co)
                    acc[co] += iv * wp[ci * D_ + co];
            }
        }
    }
    float4 o0, o1;
    o0.x = qgelu(acc[0]); o0.y = qgelu(acc[1]);
    o0.z = qgelu(acc[2]); o0.w = qgelu(acc[3]);
    o1.x = qgelu(acc[4]); o1.y = qgelu(acc[5]);
    o1.z = qgelu(acc[6]); o1.w = qgelu(acc[7]);
    float* tp = t2 + ((size_t)img * N_ + (size_t)(h0 + lh) * H_ + w) * D_;
    *(float4*)tp       = o0;
    *(float4*)(tp + 4) = o1;
}

// ---------------- Kernel 3: out = t2 @ Wu + bu ------------------------------
// (unchanged: register-weight, LDS-free, write-bound)
__global__ __launch_bounds__(256, 3) void k_up(
    const float* __restrict__ t2, const float* __restrict__ Wu,
    const float* __restrict__ bu, float* __restrict__ out, int nrows)
{
    const int wid  = threadIdx.x >> 6;
    const int lane = threadIdx.x & 63;

    float4 w[3][D_];
    float4 bias[3];
#pragma unroll
    for (int j = 0; j < 3; ++j) {
        bias[j] = *(const float4*)&bu[(lane + j * 64) * 4];
#pragma unroll
        for (int d = 0; d < D_; ++d)
            w[j][d] = *(const float4*)&Wu[d * C_ + (lane + j * 64) * 4];
    }

    const int stride = gridDim.x * 4;
    for (int row = blockIdx.x * 4 + wid; row < nrows; row += stride) {
        const float4* rp = (const float4*)(t2 + (size_t)row * D_);
        const float4 ra = rp[0];
        const float4 rb = rp[1];
        const float rv[D_] = { ra.x, ra.y, ra.z, ra.w, rb.x, rb.y, rb.z, rb.w };

#pragma unroll
        for (int j = 0; j < 3; ++j) {
            float4 o = bias[j];
#pragma unroll
            for (int d = 0; d < D_; ++d) {
                o.x += rv[d] * w[j][d].x;
                o.y += rv[d] * w[j][d].y;
                o.z += rv[d] * w[j][d].z;
                o.w += rv[d] * w[j][d].w;
            }
            *(float4*)&out[(size_t)row * C_ + (size_t)(lane + j * 64) * 4] = o;
        }
    }
}

extern "C" void kernel_launch(void* const* d_in, const int* in_sizes, int n_in,
                              void* d_out, int out_size, void* d_ws, size_t ws_size,
                              hipStream_t stream) {
    const float* x  = (const float*)d_in[0];
    const float* Wd = (const float*)d_in[1];
    const float* bd = (const float*)d_in[2];
    const float* Wc = (const float*)d_in[3];
    const float* bc = (const float*)d_in[4];
    const float* Wu = (const float*)d_in[5];
    const float* bu = (const float*)d_in[6];
    float* out = (float*)d_out;

    const int nrows = B_ * N_;                  // 65536
    float* t1 = (float*)d_ws;                   // [nrows][D_]  (2 MB)
    float* t2 = t1 + (size_t)nrows * D_;        // [nrows][D_]  (2 MB)

    // K1 v5: 512 blocks x 128 contiguous rows, DMA double-buffer pipeline.
    k_down<<<512, 256, 0, stream>>>(x, Wd, bd, t1, nrows);
    // K2: 4 blocks per image (unchanged)
    k_conv<<<B_ * 4, 256, 0, stream>>>(t1, Wc, bc, t2);
    // K3: register-weight, LDS-free (unchanged)
    k_up<<<768, 256, 0, stream>>>(t2, Wu, bu, out, nrows);
}